// Round 9
// baseline (187.529 us; speedup 1.0000x reference)
//
#include <hip/hip_runtime.h>
#include <hip/hip_bf16.h>

#define DEVI __device__ __forceinline__

typedef __attribute__((ext_vector_type(8))) short bf16x8_t;
typedef __attribute__((ext_vector_type(4))) float f32x4_t;
typedef __attribute__((ext_vector_type(16))) float f32x16_t;
typedef __attribute__((ext_vector_type(4))) short s16x4_t;
typedef __attribute__((ext_vector_type(2))) unsigned int u32x2_t;

#define QSCALE 0.18033688011112043f   /* 0.125 * log2(e): softmax in exp2 domain, m=0 fixed */
#define EXP2F(x) __builtin_amdgcn_exp2f(x)

static DEVI unsigned short f2b_bits(float f) {
    unsigned int u = __float_as_uint(f);
    unsigned int r = (u + 0x7fffu + ((u >> 16) & 1u)) >> 16;
    return (unsigned short)r;
}

static DEVI unsigned int cvtpk_bf16(float lo, float hi) {
    unsigned int r;
    asm("v_cvt_pk_bf16_f32 %0, %1, %2" : "=v"(r) : "v"(lo), "v"(hi));
    return r;
}

static DEVI bf16x8_t mk8(unsigned int a0, unsigned int a1, unsigned int a2, unsigned int a3) {
    union { unsigned int w[4]; bf16x8_t v; } u;
    u.w[0] = a0; u.w[1] = a1; u.w[2] = a2; u.w[3] = a3;
    return u.v;
}

static DEVI void gload16(const short* g, short* l) {
    __builtin_amdgcn_global_load_lds((const __attribute__((address_space(1))) void*)g,
                                     (__attribute__((address_space(3))) void*)l, 16, 0, 0);
}

#define MEMFENCE asm volatile("" ::: "memory")

// ---------------- fused prep: cast x, transpose+cast w_qkv and w_out ----------------
__global__ __launch_bounds__(256) void prep_k(const float* __restrict__ x, short* __restrict__ xb,
                                              const float* __restrict__ wqkv, short* __restrict__ wqkvT,
                                              const float* __restrict__ wout, short* __restrict__ woutT) {
    const int bid = blockIdx.x;
    const int tid = threadIdx.x;
    if (bid < 4096) {
        const long i = ((long)bid * 256 + tid) * 4;
        const float4 v = *(const float4*)(x + i);
        s16x4_t o;
        o[0] = (short)f2b_bits(v.x); o[1] = (short)f2b_bits(v.y);
        o[2] = (short)f2b_bits(v.z); o[3] = (short)f2b_bits(v.w);
        *(s16x4_t*)(xb + i) = o;
        return;
    }
    __shared__ float tile[32][33];
    const float* w; short* wT; int K, N, bx, by;
    if (bid < 4096 + 3072) {
        const int rel = bid - 4096;
        w = wqkv; wT = wqkvT; K = 1024; N = 3072; bx = rel % 96; by = rel / 96;
    } else {
        const int rel = bid - 7168;
        w = wout; wT = woutT; K = 1024; N = 1024; bx = rel & 31; by = rel >> 5;
    }
    const int n0 = bx * 32, k0 = by * 32;
    const int tx = tid & 31, ty = tid >> 5;
#pragma unroll
    for (int i = 0; i < 4; ++i)
        tile[ty + 8 * i][tx] = w[(long)(k0 + ty + 8 * i) * N + n0 + tx];
    __syncthreads();
#pragma unroll
    for (int i = 0; i < 4; ++i)
        wT[(long)(n0 + ty + 8 * i) * K + k0 + tx] = (short)f2b_bits(tile[tx][ty + 8 * i]);
}

// ---------------- GEMM: C = A @ Bt^T + bias; counted-vmcnt 2-phase pipeline ----------
template<int MODE, int NF>
__global__ __launch_bounds__(256, 3) void gemm_bt(const short* __restrict__ A,
                                                  const short* __restrict__ Bt,
                                                  const float* __restrict__ bias,
                                                  void* __restrict__ Cv,
                                                  short* __restrict__ vtp,
                                                  int M, int N, int K) {
    __shared__ __align__(16) short lsA[2][128 * 32];
    __shared__ __align__(16) short lsB[2][32 * NF * 32];
    const int tid = threadIdx.x;
    const int lane = tid & 63;
    const int w = tid >> 6;
    const int wr = w >> 1, wc = w & 1;
    const int l15 = lane & 15, lg = lane >> 4;
    const long m0 = (long)blockIdx.y * 128;
    const long n0 = (long)blockIdx.x * (32 * NF);

    f32x4_t acc[4][NF] = {};

    const int srow = tid >> 2;
    const int scol = (tid & 3) * 8;
    const short* gA = A + (m0 + srow) * (long)K + scol;
    const short* gB = Bt + (n0 + srow) * (long)K + scol;

    auto STAGE = [&](int kt, int bi) {
        gload16(gA + kt,                &lsA[bi][tid * 8]);
        gload16(gA + kt + (long)64 * K, &lsA[bi][tid * 8 + 2048]);
        gload16(gB + kt,                &lsB[bi][tid * 8]);
        if (NF == 4) gload16(gB + kt + (long)64 * K, &lsB[bi][tid * 8 + 2048]);
    };

    const int nt = K >> 5;
    STAGE(0, 0);
    int buf = 0;

    for (int i = 0; i < nt; ++i) {
        if (i + 1 < nt) {
            STAGE((i + 1) << 5, buf ^ 1);
            if (NF == 4) asm volatile("s_waitcnt vmcnt(4)" ::: "memory");
            else         asm volatile("s_waitcnt vmcnt(3)" ::: "memory");
        } else {
            asm volatile("s_waitcnt vmcnt(0)" ::: "memory");
        }
        __builtin_amdgcn_s_barrier();
        MEMFENCE;
        bf16x8_t af[4], bfr[NF];
#pragma unroll
        for (int m = 0; m < 4; ++m)
            af[m] = *(const bf16x8_t*)&lsA[buf][(wr * 64 + m * 16 + l15) * 32 + lg * 8];
#pragma unroll
        for (int n = 0; n < NF; ++n)
            bfr[n] = *(const bf16x8_t*)&lsB[buf][(wc * NF * 16 + n * 16 + l15) * 32 + lg * 8];
#pragma unroll
        for (int m = 0; m < 4; ++m)
#pragma unroll
            for (int n = 0; n < NF; ++n)
                acc[m][n] = __builtin_amdgcn_mfma_f32_16x16x32_bf16(af[m], bfr[n], acc[m][n], 0, 0, 0);
        MEMFENCE;
        __builtin_amdgcn_s_barrier();
        buf ^= 1;
    }

#pragma unroll
    for (int n = 0; n < NF; ++n) {
        const int col = (int)n0 + wc * NF * 16 + n * 16 + l15;
        const float bv = bias[col];
        if (MODE == 1) {
#pragma unroll
            for (int m = 0; m < 4; ++m) {
                const long row = m0 + wr * 64 + m * 16 + lg * 4;
#pragma unroll
                for (int j = 0; j < 4; ++j)
                    ((float*)Cv)[(row + j) * N + col] = acc[m][n][j] + bv;
            }
        } else if (col < 2048) {
            const float sc = (col < 1024) ? QSCALE : 1.0f;
#pragma unroll
            for (int m = 0; m < 4; ++m) {
                const long row = m0 + wr * 64 + m * 16 + lg * 4;
#pragma unroll
                for (int j = 0; j < 4; ++j)
                    ((short*)Cv)[(row + j) * N + col] = (short)f2b_bits((acc[m][n][j] + bv) * sc);
            }
        } else {
            const int hc = col - 2048;
            const int hh = hc >> 6, dd = hc & 63;
#pragma unroll
            for (int m = 0; m < 4; ++m) {
                const long row = m0 + wr * 64 + m * 16 + lg * 4;
                const int bb = (int)(row >> 11), tt = (int)(row & 2047);
                s16x4_t pk;
#pragma unroll
                for (int j = 0; j < 4; ++j) pk[j] = (short)f2b_bits(acc[m][n][j] + bv);
                *(s16x4_t*)&vtp[((long)(bb * 16 + hh) * 64 + dd) * 2048 + tt] = pk;
            }
        }
    }
}

// ---------------- causal flash attention — 32x32x16 MFMA, in-register P, split-kv, m=0 ----
// grid 768 = 32 bh x 24 pieces; 4 waves x 32 q-rows (QBLK=128); KV tile 64; LDS 32KB (K,V only).
// pp<8: qt=pp direct; pp>=8: qt=8+((pp-8)>>1), part=(pp-8)&1, kv split in halves -> f32 partials.
__global__ __launch_bounds__(256, 4) void attn_fwd(const short* __restrict__ qkv,
                                                   const short* __restrict__ vt,
                                                   short* __restrict__ y,
                                                   float* __restrict__ pwO0,
                                                   float* __restrict__ pwO1,
                                                   float* __restrict__ pwL) {
    __shared__ __align__(16) short lsK[2][64 * 64];
    __shared__ __align__(16) short lsV[2][64 * 64];
    const int bid = blockIdx.x;
    const int bh = bid & 31;
    const int pp = bid >> 5;
    int qt, j0, j1, part;
    if (pp < 8) { qt = pp; part = -1; j0 = 0; j1 = 2 * qt + 2; }
    else {
        const int k = pp - 8;
        qt = 8 + (k >> 1); part = k & 1;
        const int half = qt + 1;
        j0 = part ? half : 0;
        j1 = part ? (2 * qt + 2) : half;
    }
    const int b = bh >> 4, h = bh & 15;
    const int tid = threadIdx.x, w = tid >> 6, lane = tid & 63;
    const int l31 = lane & 31;
    const int hi = lane >> 5;
    const int hi4 = hi * 4;
    const int swz = (lane & 7) << 4;          // row&7 == lane&7 for all fragment rows
    const int qmin = qt * 128 + w * 32;

    // Q fragments (B operand): col=q=l31, k=d=ds*16+hi*8+j — pre-scaled by QSCALE in GEMM
    bf16x8_t qf[4];
#pragma unroll
    for (int ds = 0; ds < 4; ++ds)
        qf[ds] = *(const bf16x8_t*)&qkv[((long)b * 2048 + qmin + l31) * 3072 +
                                        h * 64 + ds * 16 + hi * 8];

    const int srow = tid >> 3;                // 0..31 (+32 for second chunk)
    const int scolb = (tid & 7) * 16;
    const int sc = (scolb ^ ((srow & 7) << 4)) >> 1;
    const short* gK = qkv + ((long)b * 2048 + srow) * 3072 + 1024 + h * 64 + sc;
    const short* gV = vt + ((long)bh * 64 + srow) * 2048 + sc;

    auto STAGE = [&](int jt, int bufi) {
        gload16(gK + (long)jt * 64 * 3072,             &lsK[bufi][tid * 8]);
        gload16(gK + (long)jt * 64 * 3072 + 32 * 3072, &lsK[bufi][tid * 8 + 2048]);
        gload16(gV + (long)jt * 64,                    &lsV[bufi][tid * 8]);
        gload16(gV + (long)jt * 64 + 32 * 2048,        &lsV[bufi][tid * 8 + 2048]);
    };

    float lrow = 0.f;
    f32x16_t oacc0 = {}, oacc1 = {};

    STAGE(j0, 0);
    int buf = 0;

    for (int j = j0; j < j1; ++j) {
        if (j + 1 < j1) {
            STAGE(j + 1, buf ^ 1);
            asm volatile("s_waitcnt vmcnt(4)" ::: "memory");
        } else {
            asm volatile("s_waitcnt vmcnt(0)" ::: "memory");
        }
        __builtin_amdgcn_s_barrier();
        MEMFENCE;

        const int base_w = qmin - j * 64;     // wave q0 minus kv tile base
        if (base_w > -32) {
            const char* Kb = (const char*)lsK[buf];
            const char* Vb = (const char*)lsV[buf];
            const bool act1 = (base_w > 0);   // kv subtile [32,64) active

            // S^T = K * Q^T : 32x32x16, A=K[kv][d], B=Q; C col=q=l31, row=kv=crow(r,hi)
            f32x16_t s0 = {}, s1 = {};
            __builtin_amdgcn_s_setprio(1);
#pragma unroll
            for (int ds = 0; ds < 4; ++ds) {
                bf16x8_t kf0 = *(const bf16x8_t*)(Kb + l31 * 128 + ((ds * 32 + hi * 16) ^ swz));
                s0 = __builtin_amdgcn_mfma_f32_32x32x16_bf16(kf0, qf[ds], s0, 0, 0, 0);
            }
            if (act1) {
#pragma unroll
                for (int ds = 0; ds < 4; ++ds) {
                    bf16x8_t kf1 = *(const bf16x8_t*)(Kb + (32 + l31) * 128 + ((ds * 32 + hi * 16) ^ swz));
                    s1 = __builtin_amdgcn_mfma_f32_32x32x16_bf16(kf1, qf[ds], s1, 0, 0, 0);
                }
            }
            __builtin_amdgcn_s_setprio(0);

            // softmax (m=0) + in-register P->A-fragments, per kv-subtile
            float lsum = 0.f;
            bf16x8_t pa0[2], pa1[2];
#pragma unroll
            for (int sb = 0; sb < 2; ++sb) {
                if (sb == 1 && !act1) break;
                const f32x16_t& sv = sb ? s1 : s0;
                const int base = base_w - sb * 32;
                const bool nm = (base < 31);
                float p[16];
#pragma unroll
                for (int r = 0; r < 16; ++r) {
                    float x = sv[r];
                    if (nm && ((r & 3) + 8 * (r >> 2) + hi4 > base + l31)) x = -3e38f;
                    x = EXP2F(x);
                    lsum += x;
                    p[r] = x;
                }
                unsigned int w0 = cvtpk_bf16(p[0], p[1]),  w1 = cvtpk_bf16(p[2], p[3]);
                unsigned int w2 = cvtpk_bf16(p[4], p[5]),  w3 = cvtpk_bf16(p[6], p[7]);
                unsigned int w4 = cvtpk_bf16(p[8], p[9]),  w5 = cvtpk_bf16(p[10], p[11]);
                unsigned int w6 = cvtpk_bf16(p[12], p[13]), w7 = cvtpk_bf16(p[14], p[15]);
                // exchange lane-halves: A-frag k = hi*8+j
                unsigned int t0 = __shfl_xor(w0, 32), t1 = __shfl_xor(w1, 32);
                unsigned int t2 = __shfl_xor(w2, 32), t3 = __shfl_xor(w3, 32);
                unsigned int t4 = __shfl_xor(w4, 32), t5 = __shfl_xor(w5, 32);
                unsigned int t6 = __shfl_xor(w6, 32), t7 = __shfl_xor(w7, 32);
                bf16x8_t f0 = mk8(hi ? t2 : w0, hi ? t3 : w1, hi ? w2 : t0, hi ? w3 : t1);
                bf16x8_t f1 = mk8(hi ? t6 : w4, hi ? t7 : w5, hi ? w6 : t4, hi ? w7 : t5);
                if (sb == 0) { pa0[0] = f0; pa0[1] = f1; }
                else         { pa1[0] = f0; pa1[1] = f1; }
            }
            lsum += __shfl_xor(lsum, 32);
            lrow += lsum;

            // O += P V : A=P[q][kv] (regs), B=V^T[d][kv] (LDS)
            __builtin_amdgcn_s_setprio(1);
#pragma unroll
            for (int dsub = 0; dsub < 2; ++dsub) {
                f32x16_t& oa = dsub ? oacc1 : oacc0;
                const int vrow = dsub * 32 + l31;
#pragma unroll
                for (int ks = 0; ks < 2; ++ks) {
                    bf16x8_t vf0 = *(const bf16x8_t*)(Vb + vrow * 128 + ((ks * 32 + hi * 16) ^ swz));
                    oa = __builtin_amdgcn_mfma_f32_32x32x16_bf16(pa0[ks], vf0, oa, 0, 0, 0);
                }
                if (act1) {
#pragma unroll
                    for (int ks = 0; ks < 2; ++ks) {
                        bf16x8_t vf1 = *(const bf16x8_t*)(Vb + vrow * 128 + ((64 + ks * 32 + hi * 16) ^ swz));
                        oa = __builtin_amdgcn_mfma_f32_32x32x16_bf16(pa1[ks], vf1, oa, 0, 0, 0);
                    }
                }
            }
            __builtin_amdgcn_s_setprio(0);
        }
        MEMFENCE;
        __builtin_amdgcn_s_barrier();
        buf ^= 1;
    }

    if (part < 0) {
        const float linv = 1.0f / lrow;       // per-lane q = l31
#pragma unroll
        for (int r = 0; r < 16; ++r) {
            const int crow = (r & 3) + 8 * (r >> 2) + hi4;
            const float lr_ = __shfl(linv, crow);
            const long row = (long)b * 2048 + qmin + crow;
            y[row * 1024 + h * 64 + l31]      = (short)f2b_bits(oacc0[r] * lr_);
            y[row * 1024 + h * 64 + 32 + l31] = (short)f2b_bits(oacc1[r] * lr_);
        }
    } else {
        float* po = (part ? pwO1 : pwO0) + ((size_t)bh * 1024 + (qmin - 1024)) * 64;
#pragma unroll
        for (int r = 0; r < 16; ++r) {
            const int crow = (r & 3) + 8 * (r >> 2) + hi4;
            po[crow * 64 + l31]      = oacc0[r];
            po[crow * 64 + 32 + l31] = oacc1[r];
        }
        if (lane < 32)
            pwL[(size_t)part * 32768 + bh * 1024 + (qmin + lane - 1024)] = lrow;
    }
}

// ---------------- combine split-kv partials for q-rows [1024, 2048) ----------------
__global__ __launch_bounds__(256) void attn_combine(const float* __restrict__ pwO0,
                                                    const float* __restrict__ pwO1,
                                                    const float* __restrict__ pwL,
                                                    short* __restrict__ y) {
    const int idx = blockIdx.x * 256 + threadIdx.x;   // 32768 rows x 64 d
    const int d = idx & 63;
    const int rr = idx >> 6;                          // bh*1024 + qr
    const int bh = rr >> 10, qr = rr & 1023;
    const int b = bh >> 4, h = bh & 15;
    const float l = pwL[rr] + pwL[32768 + rr];
    const float o = pwO0[(size_t)rr * 64 + d] + pwO1[(size_t)rr * 64 + d];
    y[((long)b * 2048 + 1024 + qr) * 1024 + h * 64 + d] = (short)f2b_bits(o / l);
}

extern "C" void kernel_launch(void* const* d_in, const int* in_sizes, int n_in,
                              void* d_out, int out_size, void* d_ws, size_t ws_size,
                              hipStream_t stream) {
    const float* x     = (const float*)d_in[0];
    const float* w_qkv = (const float*)d_in[1];
    const float* b_qkv = (const float*)d_in[2];
    const float* w_out = (const float*)d_in[3];
    const float* b_out = (const float*)d_in[4];

    char* ws = (char*)d_ws;
    short* xb    = (short*)(ws);
    float* pwO0  = (float*)(ws);                       // reuses xb region after gemm0
    short* wqkvT = (short*)(ws + (8u << 20));
    short* woutT = (short*)(ws + (14u << 20));
    short* qkvb  = (short*)(ws + (16u << 20));
    short* vt    = (short*)(ws + (40u << 20));
    short* yatt  = (short*)(ws + (48u << 20));
    float* pwO1  = (float*)(ws + (56u << 20));
    float* pwL   = (float*)(ws + (64u << 20));

    prep_k<<<8192, 256, 0, stream>>>(x, xb, w_qkv, wqkvT, w_out, woutT);
    gemm_bt<0, 4><<<dim3(24, 32), 256, 0, stream>>>(xb, wqkvT, b_qkv, (void*)qkvb, vt, 4096, 3072, 1024);
    attn_fwd<<<768, 256, 0, stream>>>(qkvb, vt, yatt, pwO0, pwO1, pwL);
    attn_combine<<<8192, 256, 0, stream>>>(pwO0, pwO1, pwL, yatt);
    gemm_bt<1, 2><<<dim3(16, 32), 256, 0, stream>>>(yatt, woutT, b_out, d_out, nullptr, 4096, 1024, 1024);
}

// Round 10
// 177.217 us; speedup vs baseline: 1.0582x; 1.0582x over previous
//
#include <hip/hip_runtime.h>
#include <hip/hip_bf16.h>

#define DEVI __device__ __forceinline__

typedef __attribute__((ext_vector_type(8))) short bf16x8_t;
typedef __attribute__((ext_vector_type(4))) float f32x4_t;
typedef __attribute__((ext_vector_type(4))) short s16x4_t;
typedef __attribute__((ext_vector_type(2))) unsigned int u32x2_t;

#define QSCALE 0.18033688011112043f   /* 0.125 * log2(e): softmax in exp2 domain, m=0 fixed */
#define EXP2F(x) __builtin_amdgcn_exp2f(x)

static DEVI unsigned short f2b_bits(float f) {
    unsigned int u = __float_as_uint(f);
    unsigned int r = (u + 0x7fffu + ((u >> 16) & 1u)) >> 16;
    return (unsigned short)r;
}

static DEVI unsigned int cvtpk_bf16(float lo, float hi) {
    unsigned int r;
    asm("v_cvt_pk_bf16_f32 %0, %1, %2" : "=v"(r) : "v"(lo), "v"(hi));
    return r;
}

static DEVI void gload16(const short* g, short* l) {
    __builtin_amdgcn_global_load_lds((const __attribute__((address_space(1))) void*)g,
                                     (__attribute__((address_space(3))) void*)l, 16, 0, 0);
}

#define MEMFENCE asm volatile("" ::: "memory")

// ---------------- fused prep: cast x, transpose+cast w_qkv and w_out ----------------
__global__ __launch_bounds__(256) void prep_k(const float* __restrict__ x, short* __restrict__ xb,
                                              const float* __restrict__ wqkv, short* __restrict__ wqkvT,
                                              const float* __restrict__ wout, short* __restrict__ woutT) {
    const int bid = blockIdx.x;
    const int tid = threadIdx.x;
    if (bid < 4096) {
        const long i = ((long)bid * 256 + tid) * 4;
        const float4 v = *(const float4*)(x + i);
        s16x4_t o;
        o[0] = (short)f2b_bits(v.x); o[1] = (short)f2b_bits(v.y);
        o[2] = (short)f2b_bits(v.z); o[3] = (short)f2b_bits(v.w);
        *(s16x4_t*)(xb + i) = o;
        return;
    }
    __shared__ float tile[32][33];
    const float* w; short* wT; int K, N, bx, by;
    if (bid < 4096 + 3072) {
        const int rel = bid - 4096;
        w = wqkv; wT = wqkvT; K = 1024; N = 3072; bx = rel % 96; by = rel / 96;
    } else {
        const int rel = bid - 7168;
        w = wout; wT = woutT; K = 1024; N = 1024; bx = rel & 31; by = rel >> 5;
    }
    const int n0 = bx * 32, k0 = by * 32;
    const int tx = tid & 31, ty = tid >> 5;
#pragma unroll
    for (int i = 0; i < 4; ++i)
        tile[ty + 8 * i][tx] = w[(long)(k0 + ty + 8 * i) * N + n0 + tx];
    __syncthreads();
#pragma unroll
    for (int i = 0; i < 4; ++i)
        wT[(long)(n0 + ty + 8 * i) * K + k0 + tx] = (short)f2b_bits(tile[tx][ty + 8 * i]);
}

// ---------------- GEMM: C = A @ Bt^T + bias; counted-vmcnt 2-phase pipeline ----------
// MODE 0 (NF=4): cols<1024 bf16*QSCALE, [1024,2048) bf16, >=2048 scattered transposed to vtp.
// MODE 1 (NF=2): f32 out + bias.
template<int MODE, int NF>
__global__ __launch_bounds__(256, 3) void gemm_bt(const short* __restrict__ A,
                                                  const short* __restrict__ Bt,
                                                  const float* __restrict__ bias,
                                                  void* __restrict__ Cv,
                                                  short* __restrict__ vtp,
                                                  int M, int N, int K) {
    __shared__ __align__(16) short lsA[2][128 * 32];
    __shared__ __align__(16) short lsB[2][32 * NF * 32];
    const int tid = threadIdx.x;
    const int lane = tid & 63;
    const int w = tid >> 6;
    const int wr = w >> 1, wc = w & 1;
    const int l15 = lane & 15, lg = lane >> 4;
    const long m0 = (long)blockIdx.y * 128;
    const long n0 = (long)blockIdx.x * (32 * NF);

    f32x4_t acc[4][NF] = {};

    const int srow = tid >> 2;
    const int scol = (tid & 3) * 8;
    const short* gA = A + (m0 + srow) * (long)K + scol;
    const short* gB = Bt + (n0 + srow) * (long)K + scol;

    auto STAGE = [&](int kt, int bi) {
        gload16(gA + kt,                &lsA[bi][tid * 8]);
        gload16(gA + kt + (long)64 * K, &lsA[bi][tid * 8 + 2048]);
        gload16(gB + kt,                &lsB[bi][tid * 8]);
        if (NF == 4) gload16(gB + kt + (long)64 * K, &lsB[bi][tid * 8 + 2048]);
    };

    const int nt = K >> 5;
    STAGE(0, 0);
    int buf = 0;

    for (int i = 0; i < nt; ++i) {
        if (i + 1 < nt) {
            STAGE((i + 1) << 5, buf ^ 1);
            if (NF == 4) asm volatile("s_waitcnt vmcnt(4)" ::: "memory");
            else         asm volatile("s_waitcnt vmcnt(3)" ::: "memory");
        } else {
            asm volatile("s_waitcnt vmcnt(0)" ::: "memory");
        }
        __builtin_amdgcn_s_barrier();
        MEMFENCE;
        bf16x8_t af[4], bfr[NF];
#pragma unroll
        for (int m = 0; m < 4; ++m)
            af[m] = *(const bf16x8_t*)&lsA[buf][(wr * 64 + m * 16 + l15) * 32 + lg * 8];
#pragma unroll
        for (int n = 0; n < NF; ++n)
            bfr[n] = *(const bf16x8_t*)&lsB[buf][(wc * NF * 16 + n * 16 + l15) * 32 + lg * 8];
#pragma unroll
        for (int m = 0; m < 4; ++m)
#pragma unroll
            for (int n = 0; n < NF; ++n)
                acc[m][n] = __builtin_amdgcn_mfma_f32_16x16x32_bf16(af[m], bfr[n], acc[m][n], 0, 0, 0);
        MEMFENCE;
        __builtin_amdgcn_s_barrier();
        buf ^= 1;
    }

#pragma unroll
    for (int n = 0; n < NF; ++n) {
        const int col = (int)n0 + wc * NF * 16 + n * 16 + l15;
        const float bv = bias[col];
        if (MODE == 1) {
#pragma unroll
            for (int m = 0; m < 4; ++m) {
                const long row = m0 + wr * 64 + m * 16 + lg * 4;
#pragma unroll
                for (int j = 0; j < 4; ++j)
                    ((float*)Cv)[(row + j) * N + col] = acc[m][n][j] + bv;
            }
        } else if (col < 2048) {
            const float sc = (col < 1024) ? QSCALE : 1.0f;
#pragma unroll
            for (int m = 0; m < 4; ++m) {
                const long row = m0 + wr * 64 + m * 16 + lg * 4;
#pragma unroll
                for (int j = 0; j < 4; ++j)
                    ((short*)Cv)[(row + j) * N + col] = (short)f2b_bits((acc[m][n][j] + bv) * sc);
            }
        } else {
            const int hc = col - 2048;
            const int hh = hc >> 6, dd = hc & 63;
#pragma unroll
            for (int m = 0; m < 4; ++m) {
                const long row = m0 + wr * 64 + m * 16 + lg * 4;
                const int bb = (int)(row >> 11), tt = (int)(row & 2047);
                s16x4_t pk;
#pragma unroll
                for (int j = 0; j < 4; ++j) pk[j] = (short)f2b_bits(acc[m][n][j] + bv);
                *(s16x4_t*)&vtp[((long)(bb * 16 + hh) * 64 + dd) * 2048 + tt] = pk;
            }
        }
    }
}

// ---------------- causal flash attention — 8-wave QBLK=128 block, split-kv, m=0 ----------
// grid 768 = 32 bh x 24 pieces; 8 waves x 16 q-rows; KV tile 64; 3 blocks/CU.
// CU-balanced piece map (blocks bid, bid+256, bid+512 co-reside; triple sums = 34 iters):
//   pp<8:   qt=pp,    direct, iters 2pp+2
//   8..15:  qt=23-pp, part0,  iters qt+1
//   16..23: qt=31-pp, part1,  iters qt+1
__global__ __launch_bounds__(512, 6) void attn_fwd(const short* __restrict__ qkv,
                                                   const short* __restrict__ vt,
                                                   short* __restrict__ y,
                                                   float* __restrict__ pwO0,
                                                   float* __restrict__ pwO1,
                                                   float* __restrict__ pwL) {
    __shared__ __align__(16) short lsK[2][64 * 64];
    __shared__ __align__(16) short lsV[2][64 * 64];
    __shared__ __align__(16) short lsP[8 * 16 * 64];
    const int bid = blockIdx.x;
    const int bh = bid & 31;
    const int pp = bid >> 5;
    int qt, j0, j1, part;
    if (pp < 8)       { qt = pp;      part = -1; j0 = 0;      j1 = 2 * qt + 2; }
    else if (pp < 16) { qt = 23 - pp; part = 0;  j0 = 0;      j1 = qt + 1;     }
    else              { qt = 31 - pp; part = 1;  j0 = qt + 1; j1 = 2 * qt + 2; }
    const int b = bh >> 4, h = bh & 15;
    const int tid = threadIdx.x, w = tid >> 6, lane = tid & 63;
    const int l15 = lane & 15, lg = lane >> 4;
    const int lg4 = lg * 4;
    const int swz = (l15 & 7) << 4;
    const int qmin = qt * 128 + w * 16;

    // Q fragments (B operand) — pre-scaled by 0.125*log2e in GEMM epilogue
    const long qrow = (long)qmin + l15;
    const bf16x8_t qf0 = *(const bf16x8_t*)&qkv[((long)b * 2048 + qrow) * 3072 + h * 64 + lg * 8];
    const bf16x8_t qf1 = *(const bf16x8_t*)&qkv[((long)b * 2048 + qrow) * 3072 + h * 64 + 32 + lg * 8];

    const int srow = tid >> 3;           // 0..63
    const int scolb = (tid & 7) * 16;
    const int sc = (scolb ^ ((srow & 7) << 4)) >> 1;
    const short* gK = qkv + ((long)b * 2048 + srow) * 3072 + 1024 + h * 64 + sc;
    const short* gV = vt + ((long)bh * 64 + srow) * 2048 + sc;

    auto STAGE = [&](int jt, int bufi) {
        gload16(gK + (long)jt * 64 * 3072, &lsK[bufi][tid * 8]);
        gload16(gV + (long)jt * 64,        &lsV[bufi][tid * 8]);
    };

    float lrow = 0.f;
    f32x4_t oacc[4] = {};

    STAGE(j0, 0);
    int buf = 0;

    char* Pb = (char*)lsP + w * 2048 + l15 * 128;

    for (int j = j0; j < j1; ++j) {
        if (j + 1 < j1) {
            STAGE(j + 1, buf ^ 1);
            asm volatile("s_waitcnt vmcnt(2)" ::: "memory");
        } else {
            asm volatile("s_waitcnt vmcnt(0)" ::: "memory");
        }
        __builtin_amdgcn_s_barrier();
        MEMFENCE;

        const int base0 = qmin - j * 64;          // wave-q0 minus kv0
        const bool active = (base0 > -16);
        if (active) {
            const bool needmask = (base0 < 63);
            const int nlim = needmask ? min(4, ((base0 + 15) >> 4) + 1) : 4;
            const char* Kb = (const char*)lsK[buf];
            const char* Vb = (const char*)lsV[buf];

            // S^T = K * Q^T : col = q = l15, row = kv = n*16 + lg4 + r
            f32x4_t s[4] = {};
            __builtin_amdgcn_s_setprio(1);
#pragma unroll
            for (int kq = 0; kq < 2; ++kq) {
                const bf16x8_t qf = kq ? qf1 : qf0;
#pragma unroll
                for (int n = 0; n < 4; ++n) {
                    if (n < nlim) {
                        bf16x8_t kf = *(const bf16x8_t*)(Kb + (n * 16 + l15) * 128 + ((kq * 64 + lg * 16) ^ swz));
                        s[n] = __builtin_amdgcn_mfma_f32_16x16x32_bf16(kf, qf, s[n], 0, 0, 0);
                    }
                }
            }
            __builtin_amdgcn_s_setprio(0);

            float p[4][4];
#pragma unroll
            for (int n = 0; n < 4; ++n)
#pragma unroll
                for (int r = 0; r < 4; ++r) p[n][r] = s[n][r];

            if (needmask) {
                const int qb = base0 + l15;       // q-local of this lane's row
#pragma unroll
                for (int n = 0; n < 4; ++n)
#pragma unroll
                    for (int r = 0; r < 4; ++r)
                        if (n * 16 + lg4 + r > qb) p[n][r] = -3e38f;
            }

            // fixed m=0: p = exp2(s) directly
            float lsum = 0.f;
#pragma unroll
            for (int n = 0; n < 4; ++n) {
                u32x2_t dw;
                if (n < nlim) {
#pragma unroll
                    for (int r = 0; r < 4; ++r) {
                        p[n][r] = EXP2F(p[n][r]);
                        lsum += p[n][r];
                    }
                    dw[0] = cvtpk_bf16(p[n][0], p[n][1]);
                    dw[1] = cvtpk_bf16(p[n][2], p[n][3]);
                } else {
                    dw[0] = 0u; dw[1] = 0u;
                }
                *(u32x2_t*)(Pb + ((n * 32 + lg * 8) ^ swz)) = dw;
            }
            lsum += __shfl_xor(lsum, 16);
            lsum += __shfl_xor(lsum, 32);
            lrow += lsum;

            asm volatile("s_waitcnt lgkmcnt(0)" ::: "memory");   // P visible (wave-local)

            // O += P V
            __builtin_amdgcn_s_setprio(1);
#pragma unroll
            for (int kk = 0; kk < 2; ++kk) {
                if (!(needmask && kk * 32 > base0 + 15)) {
                    bf16x8_t pf = *(const bf16x8_t*)(Pb + ((kk * 64 + lg * 16) ^ swz));
#pragma unroll
                    for (int n = 0; n < 4; ++n) {
                        bf16x8_t vf = *(const bf16x8_t*)(Vb + (n * 16 + l15) * 128 + ((kk * 64 + lg * 16) ^ swz));
                        oacc[n] = __builtin_amdgcn_mfma_f32_16x16x32_bf16(pf, vf, oacc[n], 0, 0, 0);
                    }
                }
            }
            __builtin_amdgcn_s_setprio(0);
        }
        MEMFENCE;
        __builtin_amdgcn_s_barrier();
        buf ^= 1;
    }

    if (part < 0) {
        float lr[4];
#pragma unroll
        for (int r = 0; r < 4; ++r) lr[r] = 1.0f / __shfl(lrow, lg4 + r);
#pragma unroll
        for (int n = 0; n < 4; ++n)
#pragma unroll
            for (int r = 0; r < 4; ++r)
                y[((long)b * 2048 + qmin + lg4 + r) * 1024 + h * 64 + n * 16 + l15] =
                    (short)f2b_bits(oacc[n][r] * lr[r]);
    } else {
        float* po = (part ? pwO1 : pwO0) + ((size_t)bh * 1024 + (qmin - 1024)) * 64;
#pragma unroll
        for (int n = 0; n < 4; ++n)
#pragma unroll
            for (int r = 0; r < 4; ++r)
                po[(lg4 + r) * 64 + n * 16 + l15] = oacc[n][r];
        if (lg == 0)
            pwL[(size_t)part * 32768 + bh * 1024 + (qmin + l15 - 1024)] = lrow;
    }
}

// ---------------- combine split-kv partials for q-rows [1024, 2048) ----------------
__global__ __launch_bounds__(256) void attn_combine(const float* __restrict__ pwO0,
                                                    const float* __restrict__ pwO1,
                                                    const float* __restrict__ pwL,
                                                    short* __restrict__ y) {
    const int idx = blockIdx.x * 256 + threadIdx.x;   // 32768 rows x 64 d
    const int d = idx & 63;
    const int rr = idx >> 6;                          // bh*1024 + qr
    const int bh = rr >> 10, qr = rr & 1023;
    const int b = bh >> 4, h = bh & 15;
    const float l = pwL[rr] + pwL[32768 + rr];
    const float o = pwO0[(size_t)rr * 64 + d] + pwO1[(size_t)rr * 64 + d];
    y[((long)b * 2048 + 1024 + qr) * 1024 + h * 64 + d] = (short)f2b_bits(o / l);
}

extern "C" void kernel_launch(void* const* d_in, const int* in_sizes, int n_in,
                              void* d_out, int out_size, void* d_ws, size_t ws_size,
                              hipStream_t stream) {
    const float* x     = (const float*)d_in[0];
    const float* w_qkv = (const float*)d_in[1];
    const float* b_qkv = (const float*)d_in[2];
    const float* w_out = (const float*)d_in[3];
    const float* b_out = (const float*)d_in[4];

    char* ws = (char*)d_ws;
    short* xb    = (short*)(ws);
    float* pwO0  = (float*)(ws);                       // reuses xb region after gemm0
    short* wqkvT = (short*)(ws + (8u << 20));
    short* woutT = (short*)(ws + (14u << 20));
    short* qkvb  = (short*)(ws + (16u << 20));
    short* vt    = (short*)(ws + (40u << 20));
    short* yatt  = (short*)(ws + (48u << 20));
    float* pwO1  = (float*)(ws + (56u << 20));
    float* pwL   = (float*)(ws + (64u << 20));

    prep_k<<<8192, 256, 0, stream>>>(x, xb, w_qkv, wqkvT, w_out, woutT);
    gemm_bt<0, 4><<<dim3(24, 32), 256, 0, stream>>>(xb, wqkvT, b_qkv, (void*)qkvb, vt, 4096, 3072, 1024);
    attn_fwd<<<768, 512, 0, stream>>>(qkvb, vt, yatt, pwO0, pwO1, pwL);
    attn_combine<<<8192, 256, 0, stream>>>(pwO0, pwO1, pwL, yatt);
    gemm_bt<1, 2><<<dim3(16, 32), 256, 0, stream>>>(yatt, woutT, b_out, d_out, nullptr, 4096, 1024, 1024);
}